// Round 13
// baseline (4552.692 us; speedup 1.0000x reference)
//
#include <hip/hip_runtime.h>
#include <hip/hip_bf16.h>

#define B_   64
#define S_   1024
#define D_   512
#define H_   512
#define NWG  256    // 256 launched; 128 active (blockIdx&7 < 4), 1 wave / CU
#define NCS  32     // column slices of 16 h-cols
#define HCW  16
#define NT   64

typedef __attribute__((ext_vector_type(8))) short short8;
typedef __attribute__((ext_vector_type(4))) float f32x4;

// Swizzled byte offset into the LDS W tile: [gc][k] bf16, row = 2048 B, 64 rows.
__device__ __forceinline__ int wl_byte(int gc, int k) {
  return ((gc << 11) + (k << 1)) ^ ((gc & 7) << 4);
}
__device__ __forceinline__ float sigm(float v) { return 1.0f / (1.0f + __expf(-v)); }
__device__ __forceinline__ float tanh_(float v) { return 1.0f - 2.0f / (__expf(2.0f * v) + 1.0f); }
__device__ __forceinline__ short f2bf(float f) {
  __hip_bfloat16 h = __float2bfloat16(f);
  short s;
  __builtin_memcpy(&s, &h, 2);
  return s;
}

union U128 { unsigned long long u[2]; unsigned int w[4]; short8 s; };

// ---------------------------------------------------------------------------
// Prep: xb = bf16(x), same [B][S][D] layout.
// ---------------------------------------------------------------------------
__global__ __launch_bounds__(256, 1) void lstm_xprep(
    const float* __restrict__ xg, short* __restrict__ xb)
{
  const size_t i = ((size_t)blockIdx.x * 256 + threadIdx.x) * 8;
  f32x4 a = *(const f32x4*)(xg + i);
  f32x4 b = *(const f32x4*)(xg + i + 4);
  short8 v;
#pragma unroll
  for (int j = 0; j < 4; ++j) { v[j] = f2bf(a[j]); v[4 + j] = f2bf(b[j]); }
  *(short8*)(xb + i) = v;
}

// Record (16B, one per (row, 8-col group)): 8 bf16 = one MFMA A-fragment.
// Step tag (t mod 4) in LSBs of col0 (bit0) / col4 (bit1); single dwordx4
// store keeps tag+data atomic. Poll-passing induction bounds staleness to
// {t, t-2}; bit1 separates. Exchange is strictly within a 16-row cohort,
// whose 32 producer waves sit (when verified) on ONE XCD -> sc0 (L2-scope).

template<int USE_XB>
__global__ __launch_bounds__(NT, 1) void lstm_persist(
    const float* __restrict__ xg, const short* __restrict__ xb,
    const float* __restrict__ Wf, const float* __restrict__ bfv,
    const float* __restrict__ Wi, const float* __restrict__ biv,
    const float* __restrict__ Wc, const float* __restrict__ bcv,
    const float* __restrict__ Wo, const float* __restrict__ bov,
    float* __restrict__ out,
    char* __restrict__ hbc,            // [2 parity][4 cohorts][16 rows][64 grp][16B]
    unsigned int* __restrict__ claims) // [4][32]: xcd+1 of each cohort member
{
  __shared__ short Wl[64 * 1024];    // 128 KB: [gc=64][k=1024] bf16, swizzled

  const int bid    = blockIdx.x;
  const int cohort = bid & 7;
  if (cohort >= 4) return;           // 128 WGs idle-exit (XCDs 4-7 class)
  const int cs   = bid >> 3;         // 0..31
  const int lane = threadIdx.x;      // single wave

  // ---- one-time: stage this WG's W slice (4 gates x 16 cols, transposed) ----
  {
    const float* Wg4[4] = {Wf, Wi, Wc, Wo};
    const int gc = lane;             // 0..63: gate = gc>>4, col = cs*16+(gc&15)
    const float* Wsrc = Wg4[gc >> 4];
    const int col = cs * HCW + (gc & 15);
    for (int k = 0; k < 1024; ++k)
      *(short*)((char*)Wl + wl_byte(gc, k)) = f2bf(Wsrc[(size_t)k * H_ + col]);
  }

  // C' lane mapping (mfma(b,a)): lane&15 = batch row, (lane>>4)*4+reg = gatecol.
  const int q    = lane >> 4;        // 0..3 -> gate-cols q*4..q*4+3 (per gate)
  const int rr   = lane & 15;        // batch row within cohort
  const int colq = cs * HCW + (q << 2);
  float bF4[4], bI4[4], bG4[4], bO4[4];
#pragma unroll
  for (int r = 0; r < 4; ++r) {
    bF4[r] = bfv[colq + r]; bI4[r] = biv[colq + r];
    bG4[r] = bcv[colq + r]; bO4[r] = bov[colq + r];
  }

  const int rowb = (cohort << 4) + rr;   // global batch row
  const int kb8  = q << 3;

  // ---- XCD self-verification: publish my XCC_ID, check cohort uniformity.
  //      Uniform -> exchange at L2 scope (sc0). Mixed/unknown -> sc1.
  //      Decision is deterministic & identical across the cohort (claims
  //      written once per launch; zeroed by the captured memset). ----
  int xcd;
  asm volatile("s_getreg_b32 %0, hwreg(HW_REG_XCC_ID)" : "=s"(xcd));
  if (lane == 0)
    __hip_atomic_store(&claims[(cohort << 5) + cs], (unsigned int)(xcd + 1),
                       __ATOMIC_RELAXED, __HIP_MEMORY_SCOPE_SYSTEM);
  unsigned int mine;
  do {
    mine = __hip_atomic_load(&claims[(cohort << 5) + (lane & 31)],
                             __ATOMIC_RELAXED, __HIP_MEMORY_SCOPE_SYSTEM);
  } while (!__all((int)(mine != 0u)));
  const unsigned int ref = (unsigned int)__shfl((int)mine, 0);
  const bool use_sc0 = (__all((int)(mine == ref)) != 0);

  __syncthreads();                   // Wl ready (single wave; nominal)

  char* cb = hbc + (cohort << 14);   // cohort base; +65536 per parity

  float cst[4] = {0.f, 0.f, 0.f, 0.f};

  for (int t = 0; t < S_; ++t) {
    const char* hrd = cb + (t & 1) * 65536;
    char*       hwr = cb + ((t + 1) & 1) * 65536;

    f32x4 aF = {0.f,0.f,0.f,0.f}, aI = {0.f,0.f,0.f,0.f};
    f32x4 aG = {0.f,0.f,0.f,0.f}, aO = {0.f,0.f,0.f,0.f};

    // ---- x-part first (no cross-WG dependency); 4 independent MFMA chains ----
    if constexpr (USE_XB) {
      const short* xr = xb + (size_t)rowb * S_ * D_ + (size_t)t * D_;
#pragma unroll 4
      for (int ks = 0; ks < 16; ++ks) {
        const int kx = ks * 32 + kb8;
        short8 a = *(const short8*)(xr + kx);
        const int kw = 512 + kx;
        short8 bF = *(const short8*)((const char*)Wl + wl_byte(rr, kw));
        short8 bI = *(const short8*)((const char*)Wl + wl_byte(16 + rr, kw));
        short8 bG = *(const short8*)((const char*)Wl + wl_byte(32 + rr, kw));
        short8 bO = *(const short8*)((const char*)Wl + wl_byte(48 + rr, kw));
        aF = __builtin_amdgcn_mfma_f32_16x16x32_bf16(bF, a, aF, 0, 0, 0);
        aI = __builtin_amdgcn_mfma_f32_16x16x32_bf16(bI, a, aI, 0, 0, 0);
        aG = __builtin_amdgcn_mfma_f32_16x16x32_bf16(bG, a, aG, 0, 0, 0);
        aO = __builtin_amdgcn_mfma_f32_16x16x32_bf16(bO, a, aO, 0, 0, 0);
      }
    } else {
      const float* xr = xg + (size_t)rowb * S_ * D_ + (size_t)t * D_;
#pragma unroll 4
      for (int ks = 0; ks < 16; ++ks) {
        const int kx = ks * 32 + kb8;
        f32x4 f0 = *(const f32x4*)(xr + kx);
        f32x4 f1 = *(const f32x4*)(xr + kx + 4);
        short8 a;
#pragma unroll
        for (int j = 0; j < 4; ++j) { a[j] = f2bf(f0[j]); a[4 + j] = f2bf(f1[j]); }
        const int kw = 512 + kx;
        short8 bF = *(const short8*)((const char*)Wl + wl_byte(rr, kw));
        short8 bI = *(const short8*)((const char*)Wl + wl_byte(16 + rr, kw));
        short8 bG = *(const short8*)((const char*)Wl + wl_byte(32 + rr, kw));
        short8 bO = *(const short8*)((const char*)Wl + wl_byte(48 + rr, kw));
        aF = __builtin_amdgcn_mfma_f32_16x16x32_bf16(bF, a, aF, 0, 0, 0);
        aI = __builtin_amdgcn_mfma_f32_16x16x32_bf16(bI, a, aI, 0, 0, 0);
        aG = __builtin_amdgcn_mfma_f32_16x16x32_bf16(bG, a, aG, 0, 0, 0);
        aO = __builtin_amdgcn_mfma_f32_16x16x32_bf16(bO, a, aO, 0, 0, 0);
      }
    }

    // ---- h-part: serial tagged poll (R11 structure verbatim; scope varies).
    //      Lane needs records (rr, g=ks*4+q): base rr*1024 + q*16, stride
    //      64B, 16 loads; 4 q-groups coalesce per 64B line. vmcnt(0) also
    //      drains our previous-step record stores (parity-reuse induction). ----
    U128 rc0, rc1, rc2, rc3, rc4, rc5, rc6, rc7,
         rc8, rc9, rc10, rc11, rc12, rc13, rc14, rc15;
    {
      const char* rb = hrd + (rr << 10) + (q << 4);
      const unsigned int t0 = (unsigned int)t;
      const unsigned int t1 = (unsigned int)t >> 1;
#define TCHK(R) ( ((R.w[0] ^ t0) & 1u) | ((R.w[2] ^ t1) & 1u) )
#define POLLBODY(FLAGS)                                                        \
      while (true) {                                                           \
        asm volatile(                                                          \
          "global_load_dwordx4 %[r0], %[p], off " FLAGS "\n\t"                 \
          "global_load_dwordx4 %[r1], %[p], off offset:64 " FLAGS "\n\t"       \
          "global_load_dwordx4 %[r2], %[p], off offset:128 " FLAGS "\n\t"      \
          "global_load_dwordx4 %[r3], %[p], off offset:192 " FLAGS "\n\t"      \
          "global_load_dwordx4 %[r4], %[p], off offset:256 " FLAGS "\n\t"      \
          "global_load_dwordx4 %[r5], %[p], off offset:320 " FLAGS "\n\t"      \
          "global_load_dwordx4 %[r6], %[p], off offset:384 " FLAGS "\n\t"      \
          "global_load_dwordx4 %[r7], %[p], off offset:448 " FLAGS "\n\t"      \
          "global_load_dwordx4 %[r8], %[p], off offset:512 " FLAGS "\n\t"      \
          "global_load_dwordx4 %[r9], %[p], off offset:576 " FLAGS "\n\t"      \
          "global_load_dwordx4 %[r10], %[p], off offset:640 " FLAGS "\n\t"     \
          "global_load_dwordx4 %[r11], %[p], off offset:704 " FLAGS "\n\t"     \
          "global_load_dwordx4 %[r12], %[p], off offset:768 " FLAGS "\n\t"     \
          "global_load_dwordx4 %[r13], %[p], off offset:832 " FLAGS "\n\t"     \
          "global_load_dwordx4 %[r14], %[p], off offset:896 " FLAGS "\n\t"     \
          "global_load_dwordx4 %[r15], %[p], off offset:960 " FLAGS "\n\t"     \
          "s_waitcnt vmcnt(0)"                                                 \
          : [r0]"=&v"(rc0.s), [r1]"=&v"(rc1.s), [r2]"=&v"(rc2.s),              \
            [r3]"=&v"(rc3.s), [r4]"=&v"(rc4.s), [r5]"=&v"(rc5.s),              \
            [r6]"=&v"(rc6.s), [r7]"=&v"(rc7.s), [r8]"=&v"(rc8.s),              \
            [r9]"=&v"(rc9.s), [r10]"=&v"(rc10.s), [r11]"=&v"(rc11.s),          \
            [r12]"=&v"(rc12.s), [r13]"=&v"(rc13.s), [r14]"=&v"(rc14.s),        \
            [r15]"=&v"(rc15.s)                                                 \
          : [p]"v"(rb)                                                         \
          : "memory");                                                         \
        const unsigned int bad =                                               \
            TCHK(rc0)  | TCHK(rc1)  | TCHK(rc2)  | TCHK(rc3)  |                \
            TCHK(rc4)  | TCHK(rc5)  | TCHK(rc6)  | TCHK(rc7)  |                \
            TCHK(rc8)  | TCHK(rc9)  | TCHK(rc10) | TCHK(rc11) |                \
            TCHK(rc12) | TCHK(rc13) | TCHK(rc14) | TCHK(rc15);                 \
        if (__all((int)(bad == 0u))) break;                                    \
      }
      if (use_sc0) { POLLBODY("sc0") } else { POLLBODY("sc1") }
#undef POLLBODY
#undef TCHK
    }

#define HS(KS, RA)                                                             \
    {                                                                          \
      const int k0_ = (KS) * 32 + kb8;                                         \
      short8 bF_ = *(const short8*)((const char*)Wl + wl_byte(rr, k0_));       \
      short8 bI_ = *(const short8*)((const char*)Wl + wl_byte(16 + rr, k0_));  \
      short8 bG_ = *(const short8*)((const char*)Wl + wl_byte(32 + rr, k0_));  \
      short8 bO_ = *(const short8*)((const char*)Wl + wl_byte(48 + rr, k0_));  \
      aF = __builtin_amdgcn_mfma_f32_16x16x32_bf16(bF_, RA.s, aF, 0, 0, 0);    \
      aI = __builtin_amdgcn_mfma_f32_16x16x32_bf16(bI_, RA.s, aI, 0, 0, 0);    \
      aG = __builtin_amdgcn_mfma_f32_16x16x32_bf16(bG_, RA.s, aG, 0, 0, 0);    \
      aO = __builtin_amdgcn_mfma_f32_16x16x32_bf16(bO_, RA.s, aO, 0, 0, 0);    \
    }
    HS(0,  rc0)  HS(1,  rc1)  HS(2,  rc2)  HS(3,  rc3)
    HS(4,  rc4)  HS(5,  rc5)  HS(6,  rc6)  HS(7,  rc7)
    HS(8,  rc8)  HS(9,  rc9)  HS(10, rc10) HS(11, rc11)
    HS(12, rc12) HS(13, rc13) HS(14, rc14) HS(15, rc15)
#undef HS

    // ---- epilogue: lane owns all 4 gates for its 4 cols -> no shuffles ----
    float hv[4];
#pragma unroll
    for (int r = 0; r < 4; ++r) {
      const float fg = sigm(aF[r] + bF4[r]);
      const float ig = sigm(aI[r] + bI4[r]);
      const float gg = tanh_(aG[r] + bG4[r]);
      const float og = sigm(aO[r] + bO4[r]);
      const float cn = cst[r] * fg + gg * ig;
      cst[r] = cn;
      hv[r] = og * tanh_(cn);
    }

    // ---- record broadcast: merge col-quads across lane^16 (q0+q1 -> group
    //      2cs, q2+q3 -> group 2cs+1); one tagged 16B store per record ----
    unsigned long long hp8;
    {
      unsigned int l32 = (unsigned int)(unsigned short)f2bf(hv[0])
                       | ((unsigned int)(unsigned short)f2bf(hv[1]) << 16);
      unsigned int h32 = (unsigned int)(unsigned short)f2bf(hv[2])
                       | ((unsigned int)(unsigned short)f2bf(hv[3]) << 16);
      hp8 = (unsigned long long)l32 | ((unsigned long long)h32 << 32);
    }
    unsigned long long part = __shfl_xor(hp8, 16);
    if ((q & 1) == 0 && t < S_ - 1) {
      const int g = (cs << 1) + (q >> 1);
      const unsigned int tag = (unsigned int)(t + 1);
      U128 u;
      u.w[0] = ((unsigned int)hp8 & ~1u) | (tag & 1u);          // col0 LSB=bit0
      u.w[1] = (unsigned int)(hp8 >> 32);
      u.w[2] = ((unsigned int)part & ~1u) | ((tag >> 1) & 1u);  // col4 LSB=bit1
      u.w[3] = (unsigned int)(part >> 32);
      void* dst = hwr + (rr << 10) + (g << 4);
      if (use_sc0) {
        asm volatile("global_store_dwordx4 %0, %1, off sc0"
                     :: "v"(dst), "v"(u.s) : "memory");
      } else {
        asm volatile("global_store_dwordx4 %0, %1, off sc1"
                     :: "v"(dst), "v"(u.s) : "memory");
      }
    }

    // ---- out: every lane stores its unique (row, 4-col) quad, f32 ----
    {
      f32x4 hv4;
#pragma unroll
      for (int r = 0; r < 4; ++r) hv4[r] = hv[r];
      *(f32x4*)(out + (size_t)rowb * ((size_t)S_ * H_) + (size_t)t * H_ + colq) = hv4;
      if (t == S_ - 1) {
        f32x4 c4;
#pragma unroll
        for (int r = 0; r < 4; ++r) c4[r] = cst[r];
        *(f32x4*)(out + (size_t)B_ * S_ * H_ + (size_t)rowb * H_ + colq) = hv4;
        *(f32x4*)(out + (size_t)B_ * S_ * H_ + (size_t)B_ * H_
                      + (size_t)rowb * H_ + colq) = c4;
      }
    }
    // No drain, no flag, no barrier: tags ride with the data.
  }
}

extern "C" void kernel_launch(void* const* d_in, const int* in_sizes, int n_in,
                              void* d_out, int out_size, void* d_ws, size_t ws_size,
                              hipStream_t stream) {
  (void)in_sizes; (void)n_in; (void)out_size;
  const float* x  = (const float*)d_in[0];
  const float* Wf = (const float*)d_in[1];
  const float* bf = (const float*)d_in[2];
  const float* Wi = (const float*)d_in[3];
  const float* bi = (const float*)d_in[4];
  const float* Wc = (const float*)d_in[5];
  const float* bc = (const float*)d_in[6];
  const float* Wo = (const float*)d_in[7];
  const float* bo = (const float*)d_in[8];
  float* out = (float*)d_out;

  unsigned int* claims = (unsigned int*)d_ws;      // 512B used
  char* hbc = (char*)d_ws + 4096;                  // 128KB records

  const size_t XB_OFF   = (size_t)1 << 20;                        // 1 MB
  const size_t XB_BYTES = (size_t)B_ * S_ * D_ * sizeof(short);   // 64 MB

  // zero claims + both record parities (tag 0 == t=0 mod 4, data 0 == h_0);
  // captured in the graph, so every replay self-organizes cleanly.
  hipMemsetAsync(d_ws, 0, 4096 + 2 * 4 * 16384, stream);

  if (ws_size >= XB_OFF + XB_BYTES) {
    short* xb = (short*)((char*)d_ws + XB_OFF);
    lstm_xprep<<<dim3((B_ * S_ * D_) / (256 * 8)), dim3(256), 0, stream>>>(x, xb);
    lstm_persist<1><<<dim3(NWG), dim3(NT), 0, stream>>>(
        x, xb, Wf, bf, Wi, bi, Wc, bc, Wo, bo, out, hbc, claims);
  } else {
    lstm_persist<0><<<dim3(NWG), dim3(NT), 0, stream>>>(
        x, nullptr, Wf, bf, Wi, bi, Wc, bc, Wo, bo, out, hbc, claims);
  }
}